// Round 1
// baseline (173.356 us; speedup 1.0000x reference)
//
#include <hip/hip_runtime.h>
#include <hip/hip_bf16.h>

typedef __hip_bfloat16 bf16;
typedef __attribute__((ext_vector_type(8))) short s8v;   // 8 bf16 = 4 VGPR (MFMA A/B frag)
typedef __attribute__((ext_vector_type(4))) float f4v;   // MFMA C/D frag

__device__ __forceinline__ ushort f2u(float f) {
    bf16 h = __float2bfloat16(f);
    return *(ushort*)&h;
}

// ---------------------------------------------------------------------------
// B=4, C=256, H=W=64, N=4096. All inputs/outputs fp32; internal bf16.
// ws: cat bf16 [16384][512]   @ 0          (16 MiB)
//     Qb  bf16 [16384][32]    @ 16777216   ( 1 MiB)
//     Kb  bf16 [16384][32]    @ 17825792   ( 1 MiB)
//     Vf  bf16 frag-ordered   @ 18874368   ( 8 MiB)
//     Wf  bf16 frag-ordered   @ 27262976   ( 320 KiB)
// Vf: element (b,c,n) at b<<20 + (n>>5)*8192 + (c>>4)*512 + ((n>>3)&3)*128
//     + (c&15)*8 + (n&7)  -> MFMA B-frag = contiguous 1KB per wave.
// Wf: element (o,k) at (k>>5)*10240 + (o>>4)*512 + ((k>>3)&3)*128 + (o&15)*8
//     + (k&7)             -> same property.
// MFMA 16x16x32 bf16 layouts (m89/m120-verified):
//   A: lane holds A[m=lane&15][k=(lane>>4)*8+j]
//   B: lane holds B[k=(lane>>4)*8+j][n=lane&15]
//   C/D: lane holds D[row=(lane>>4)*4+r][col=lane&15]
// ---------------------------------------------------------------------------

// Kernel 1: 3x3 avg(/9, include-pad) + 3x3 max; blocks >=1024 do the W
// fp32->bf16 frag-order conversion (folded wcvt: one fewer dispatch).
__global__ __launch_bounds__(256) void pool_kernel(
    const float* __restrict__ x, ushort* __restrict__ cat,
    const float* __restrict__ wb, const float* __restrict__ wc,
    const float* __restrict__ wd, ushort* __restrict__ Wf) {
    int bid = blockIdx.x;
    int tid = threadIdx.x;
    if (bid >= 1024) {            // wcvt tail: 80 blocks x 4 frags
        int f = (bid - 1024) * 4 + (tid >> 6);   // 0..319
        int l = tid & 63;
        int ot = f % 20, kc = f / 20;
        int o = ot * 16 + (l & 15);
        int k0 = kc * 32 + (l >> 4) * 8;
        const float* wr = (o < 32) ? wb + (size_t)o * 512
                        : (o < 64) ? wc + (size_t)(o - 32) * 512
                                   : wd + (size_t)(o - 64) * 512;
        float4 f0 = *(const float4*)(wr + k0);
        float4 f1 = *(const float4*)(wr + k0 + 4);
        ushort tmp[8] = {f2u(f0.x), f2u(f0.y), f2u(f0.z), f2u(f0.w),
                         f2u(f1.x), f2u(f1.y), f2u(f1.z), f2u(f1.w)};
        *(uint4*)(Wf + kc * 10240 + ot * 512 + l * 8) = *(uint4*)tmp;
        return;
    }
    __shared__ float Xs[3][64][66];
    int b = bid >> 8, h = (bid >> 2) & 63, cg = bid & 3;
    bool hasU = (h > 0), hasD = (h < 63);
    #pragma unroll
    for (int pp = 0; pp < 12; ++pp) {
        int linear = pp * 256 + tid;
        int w4 = linear & 15;
        int cs = (linear >> 4) & 63;
        int dh = linear >> 10;
        int hh = h + dh - 1;
        float4 f = {0.f, 0.f, 0.f, 0.f};
        if ((unsigned)hh < 64u)
            f = *(const float4*)(x + ((size_t)(b * 256 + cg * 64 + cs)) * 4096
                                 + hh * 64 + w4 * 4);
        Xs[dh][w4 * 4 + 0][cs] = f.x;
        Xs[dh][w4 * 4 + 1][cs] = f.y;
        Xs[dh][w4 * 4 + 2][cs] = f.z;
        Xs[dh][w4 * 4 + 3][cs] = f.w;
    }
    __syncthreads();
    int cs = tid & 63, ws = tid >> 6;
    float vs[18], vm[18];
    #pragma unroll
    for (int j = 0; j < 18; ++j) {
        int w = ws * 16 - 1 + j;
        if ((unsigned)w < 64u) {
            float u = Xs[0][w][cs], m = Xs[1][w][cs], d = Xs[2][w][cs];
            vs[j] = u + m + d;
            float mx = m;
            if (hasU) mx = fmaxf(mx, u);
            if (hasD) mx = fmaxf(mx, d);
            vm[j] = mx;
        } else { vs[j] = 0.f; vm[j] = -3.4e38f; }
    }
    size_t nb = ((size_t)b * 4096 + h * 64 + ws * 16) * 512 + cg * 64 + cs;
    #pragma unroll
    for (int i = 0; i < 16; ++i) {
        float sum = vs[i] + vs[i + 1] + vs[i + 2];
        float mx  = fmaxf(fmaxf(vm[i], vm[i + 1]), vm[i + 2]);
        cat[nb + (size_t)i * 512]       = f2u(sum * (1.f / 9.f));
        cat[nb + (size_t)i * 512 + 256] = f2u(mx);
    }
}

// Kernel 2: single-pass projections (unchanged from r7).
__global__ __launch_bounds__(256, 2) void proj_kernel(
    const ushort* __restrict__ cat, const ushort* __restrict__ Wf,
    const float* __restrict__ bb, const float* __restrict__ bc,
    const float* __restrict__ bd,
    ushort* __restrict__ Qb, ushort* __restrict__ Kb, ushort* __restrict__ Vf) {
    __shared__ __align__(16) ushort As[32][72];
    __shared__ __align__(16) ushort Vls[256][40];
    int tid = threadIdx.x;
    int l = tid & 63, w = tid >> 6;
    int lm = l & 15, q = l >> 4;
    int n0 = blockIdx.x * 32;
    f4v acc[2][5];
    #pragma unroll
    for (int mt = 0; mt < 2; ++mt)
        #pragma unroll
        for (int ot = 0; ot < 5; ++ot)
            #pragma unroll
            for (int i = 0; i < 4; ++i) acc[mt][ot][i] = 0.f;

    const ushort* wfb = Wf + (w * 5) * 512 + l * 8;
    int sr = tid >> 3, sko = (tid & 7) * 8;
    const ushort* srow = cat + (size_t)(n0 + sr) * 512 + sko;

    for (int kc = 0; kc < 8; ++kc) {
        *(uint4*)&As[sr][sko] = *(const uint4*)(srow + kc * 64);
        __syncthreads();
        #pragma unroll
        for (int ks = 0; ks < 2; ++ks) {
            int kci = kc * 2 + ks;
            s8v bf[5];
            #pragma unroll
            for (int ot = 0; ot < 5; ++ot)
                bf[ot] = *(const s8v*)(wfb + kci * 10240 + ot * 512);
            s8v a0 = *(const s8v*)&As[lm][ks * 32 + q * 8];
            s8v a1 = *(const s8v*)&As[16 + lm][ks * 32 + q * 8];
            #pragma unroll
            for (int ot = 0; ot < 5; ++ot) {
                acc[0][ot] = __builtin_amdgcn_mfma_f32_16x16x32_bf16(a0, bf[ot], acc[0][ot], 0, 0, 0);
                acc[1][ot] = __builtin_amdgcn_mfma_f32_16x16x32_bf16(a1, bf[ot], acc[1][ot], 0, 0, 0);
            }
        }
        __syncthreads();
    }
    #pragma unroll
    for (int ot = 0; ot < 5; ++ot) {
        int o = w * 80 + ot * 16 + lm;
        if (o < 32) {
            float bias = bb[o];
            #pragma unroll
            for (int mt = 0; mt < 2; ++mt)
                #pragma unroll
                for (int r = 0; r < 4; ++r)
                    Qb[(size_t)(n0 + mt * 16 + q * 4 + r) * 32 + o]
                        = f2u(acc[mt][ot][r] + bias);
        } else if (o < 64) {
            float bias = bc[o - 32];
            #pragma unroll
            for (int mt = 0; mt < 2; ++mt)
                #pragma unroll
                for (int r = 0; r < 4; ++r)
                    Kb[(size_t)(n0 + mt * 16 + q * 4 + r) * 32 + (o - 32)]
                        = f2u(acc[mt][ot][r] + bias);
        } else {
            int c = o - 64;
            float bias = bd[c];
            #pragma unroll
            for (int mt = 0; mt < 2; ++mt) {
                ushort tmp[4];
                #pragma unroll
                for (int r = 0; r < 4; ++r) tmp[r] = f2u(acc[mt][ot][r] + bias);
                *(uint2*)&Vls[c][mt * 16 + q * 4] = *(uint2*)tmp;
            }
        }
    }
    __syncthreads();
    {
        int bidx = n0 >> 12;
        size_t fb = ((size_t)bidx << 20) + (size_t)((n0 & 4095) >> 5) * 8192 + l * 8;
        #pragma unroll
        for (int i = 0; i < 4; ++i) {
            int cb = w * 4 + i;
            *(uint4*)(Vf + fb + cb * 512) = *(const uint4*)&Vls[cb * 16 + lm][q * 8];
        }
    }
}

// Kernel 3: MFMA flash attention + residual. 256 blocks, 1024 threads
// (16 waves = 4 waves/SIMD: was 8 waves = 2/SIMD -> latency-bound, 54% idle).
// Score role:  wave w = (msw = w>>2, nsw = w&3): one 16x16 S chunk, 4 exps.
// PV role:     wave w = (cs = w&7, kh = w>>3): 32 channels (acc[4][2]),
//              k-half kh; 4 A-frag LDS reads + 2 V-frag global loads/tile.
// Per-CU/tile: 144 MFMA (~700cy/SIMD), LDS ~72KB (~560cy), VMEM ~48KB.
// One barrier per tile; PV MFMAs placed between score-MFMA and its exp to
// hide the S->exp dependency. K prefetch dist 2, V dist 1, reg ping-pong.
__global__ __launch_bounds__(1024, 4) void attn_kernel(
    const ushort* __restrict__ Qb, const ushort* __restrict__ Kb,
    const ushort* __restrict__ Vf, const float* __restrict__ x,
    const float* __restrict__ alphap, float* __restrict__ out) {
    __shared__ __align__(16) ushort Ps[2][64][72];
    __shared__ float Obuf[8][64][17];
    __shared__ float Lpart[4][64];
    __shared__ float Lrow[64];
    int tid = threadIdx.x;
    int l = tid & 63, w = tid >> 6;
    int lm = l & 15, q = l >> 4;
    int nsw = w & 3, msw = w >> 2;     // score role
    int cs = w & 7, kh = w >> 3;       // PV role
    int bid = blockIdx.x;
    int xcd = bid & 7;
    int b = xcd & 3;
    int midx = (bid >> 3) + ((xcd >> 2) << 5);
    int m0 = midx << 6;
    size_t bN = (size_t)b << 12;

    s8v Qf = *(const s8v*)(Qb + (bN + m0 + msw * 16 + lm) * 32 + q * 8);
    const ushort* kbp = Kb + (bN + nsw * 16 + lm) * 32 + q * 8;
    const ushort* vfp = Vf + ((size_t)b << 20) + kh * 8192 + (2 * cs) * 512 + l * 8;

    f4v acc[4][2];
    #pragma unroll
    for (int mt = 0; mt < 4; ++mt)
        #pragma unroll
        for (int ct = 0; ct < 2; ++ct)
            #pragma unroll
            for (int i = 0; i < 4; ++i) acc[mt][ct][i] = 0.f;
    float La = 0.f;

    // prologue: kf0 = tile0, kf1 = tile1, vfA = tile0; compute P(0)
    s8v kf0 = *(const s8v*)kbp;
    s8v kf1 = *(const s8v*)(kbp + 2048);
    s8v vfA[2], vfB[2];
    vfA[0] = *(const s8v*)(vfp);
    vfA[1] = *(const s8v*)(vfp + 512);
    {
        f4v S = {0.f, 0.f, 0.f, 0.f};
        S = __builtin_amdgcn_mfma_f32_16x16x32_bf16(kf0, Qf, S, 0, 0, 0);
        ushort e0[4];
        #pragma unroll
        for (int r = 0; r < 4; ++r) {
            float f0 = __expf(fminf(S[r], 60.f));
            La += f0; e0[r] = f2u(f0);
        }
        *(uint2*)&Ps[0][msw * 16 + lm][nsw * 16 + q * 4] = *(uint2*)e0;
    }
    __syncthreads();

// Phase(t): S(t+1) MFMA first; prefetch kf(t+2), vf(t+1); Af<-Ps[p];
// PV(t) x8 (hides S latency); exp(t+1)+Ps[1-p] write; barrier.
#define TILE_BODY(TT, KFS, KFP, VCUR, VNXT)                                       \
    {                                                                             \
        int p = (TT) & 1;                                                         \
        f4v S = {0.f, 0.f, 0.f, 0.f};                                             \
        if ((TT) < 63)                                                            \
            S = __builtin_amdgcn_mfma_f32_16x16x32_bf16(KFS, Qf, S, 0, 0, 0);     \
        if ((TT) < 62) KFP = *(const s8v*)(kbp + (size_t)((TT) + 2) * 2048);      \
        if ((TT) < 63) {                                                          \
            const ushort* vn = vfp + (size_t)((TT) + 1) * 16384;                  \
            VNXT[0] = *(const s8v*)(vn);                                          \
            VNXT[1] = *(const s8v*)(vn + 512);                                    \
        }                                                                         \
        s8v Af0 = *(const s8v*)&Ps[p][lm][kh * 32 + q * 8];                       \
        s8v Af1 = *(const s8v*)&Ps[p][16 + lm][kh * 32 + q * 8];                  \
        s8v Af2 = *(const s8v*)&Ps[p][32 + lm][kh * 32 + q * 8];                  \
        s8v Af3 = *(const s8v*)&Ps[p][48 + lm][kh * 32 + q * 8];                  \
        _Pragma("unroll")                                                         \
        for (int ct = 0; ct < 2; ++ct) {                                          \
            acc[0][ct] = __builtin_amdgcn_mfma_f32_16x16x32_bf16(Af0, VCUR[ct], acc[0][ct], 0, 0, 0); \
            acc[1][ct] = __builtin_amdgcn_mfma_f32_16x16x32_bf16(Af1, VCUR[ct], acc[1][ct], 0, 0, 0); \
            acc[2][ct] = __builtin_amdgcn_mfma_f32_16x16x32_bf16(Af2, VCUR[ct], acc[2][ct], 0, 0, 0); \
            acc[3][ct] = __builtin_amdgcn_mfma_f32_16x16x32_bf16(Af3, VCUR[ct], acc[3][ct], 0, 0, 0); \
        }                                                                         \
        if ((TT) < 63) {                                                          \
            ushort e0[4];                                                         \
            _Pragma("unroll")                                                     \
            for (int r = 0; r < 4; ++r) {                                         \
                float f0 = __expf(fminf(S[r], 60.f));                             \
                La += f0; e0[r] = f2u(f0);                                        \
            }                                                                     \
            *(uint2*)&Ps[1 - p][msw * 16 + lm][nsw * 16 + q * 4] = *(uint2*)e0;   \
        }                                                                         \
        __syncthreads();                                                          \
    }

    for (int t = 0; t < 64; t += 2) {
        TILE_BODY(t,     kf1, kf0, vfA, vfB);
        TILE_BODY(t + 1, kf0, kf1, vfB, vfA);
    }
#undef TILE_BODY

    // L: reduce over q groups (n-dir) within wave, then across nsw waves
    La += __shfl_xor(La, 16, 64);
    La += __shfl_xor(La, 32, 64);
    if (q == 0) Lpart[nsw][msw * 16 + lm] = La;
    __syncthreads();
    if (tid < 64)
        Lrow[tid] = Lpart[0][tid] + Lpart[1][tid] + Lpart[2][tid] + Lpart[3][tid];
    __syncthreads();
    // combine k-halves through LDS (kh=1 partial -> kh=0)
    #pragma unroll
    for (int ct = 0; ct < 2; ++ct) {
        if (kh == 1) {
            #pragma unroll
            for (int mt = 0; mt < 4; ++mt)
                #pragma unroll
                for (int r = 0; r < 4; ++r)
                    Obuf[cs][mt * 16 + q * 4 + r][lm] = acc[mt][ct][r];
        }
        __syncthreads();
        if (kh == 0) {
            #pragma unroll
            for (int mt = 0; mt < 4; ++mt)
                #pragma unroll
                for (int r = 0; r < 4; ++r)
                    acc[mt][ct][r] += Obuf[cs][mt * 16 + q * 4 + r][lm];
        }
        __syncthreads();
    }
    if (kh == 0) {
        float alpha = alphap[0];
        float ra = 1.f - alpha;
        #pragma unroll
        for (int mt = 0; mt < 4; ++mt) {
            float i0 = 1.f / Lrow[mt * 16 + q * 4 + 0];
            float i1 = 1.f / Lrow[mt * 16 + q * 4 + 1];
            float i2 = 1.f / Lrow[mt * 16 + q * 4 + 2];
            float i3 = 1.f / Lrow[mt * 16 + q * 4 + 3];
            #pragma unroll
            for (int ct = 0; ct < 2; ++ct) {
                int cc = cs * 32 + ct * 16 + lm;
                size_t base = ((size_t)(b * 256 + cc)) * 4096 + m0 + mt * 16 + q * 4;
                float4 xv = *(const float4*)(x + base);
                float4 ov;
                ov.x = alpha * (acc[mt][ct][0] * i0) + ra * xv.x;
                ov.y = alpha * (acc[mt][ct][1] * i1) + ra * xv.y;
                ov.z = alpha * (acc[mt][ct][2] * i2) + ra * xv.z;
                ov.w = alpha * (acc[mt][ct][3] * i3) + ra * xv.w;
                *(float4*)(out + base) = ov;
            }
        }
    }
}

extern "C" void kernel_launch(void* const* d_in, const int* in_sizes, int n_in,
                              void* d_out, int out_size, void* d_ws, size_t ws_size,
                              hipStream_t stream) {
    const float* x  = (const float*)d_in[0];
    const float* wb = (const float*)d_in[1];
    const float* bb = (const float*)d_in[2];
    const float* wc = (const float*)d_in[3];
    const float* bc = (const float*)d_in[4];
    const float* wd = (const float*)d_in[5];
    const float* bd = (const float*)d_in[6];
    const float* al = (const float*)d_in[7];
    float* out = (float*)d_out;

    char* ws = (char*)d_ws;
    ushort* cat = (ushort*)ws;                    // 16 MiB
    ushort* Qb  = (ushort*)(ws + 16777216);       //  1 MiB
    ushort* Kb  = (ushort*)(ws + 17825792);       //  1 MiB
    ushort* Vf  = (ushort*)(ws + 18874368);       //  8 MiB (frag-ordered)
    ushort* Wf  = (ushort*)(ws + 27262976);       //  320 KiB (frag-ordered)

    pool_kernel<<<dim3(1104), dim3(256), 0, stream>>>(x, cat, wb, wc, wd, Wf);
    proj_kernel<<<dim3(512), dim3(256), 0, stream>>>(cat, Wf, bb, bc, bd,
                                                     Qb, Kb, Vf);
    attn_kernel<<<dim3(256), dim3(1024), 0, stream>>>(Qb, Kb, Vf, x, al, out);
}

// Round 2
// 167.028 us; speedup vs baseline: 1.0379x; 1.0379x over previous
//
#include <hip/hip_runtime.h>
#include <hip/hip_bf16.h>

typedef __hip_bfloat16 bf16;
typedef __attribute__((ext_vector_type(8))) short s8v;   // 8 bf16 = 4 VGPR (MFMA A/B frag)
typedef __attribute__((ext_vector_type(4))) float f4v;   // MFMA C/D frag

__device__ __forceinline__ ushort f2u(float f) {
    bf16 h = __float2bfloat16(f);
    return *(ushort*)&h;
}

// ---------------------------------------------------------------------------
// B=4, C=256, H=W=64, N=4096. All inputs/outputs fp32; internal bf16.
// ws: cat bf16 [16384][512]   @ 0          (16 MiB)
//     Qb  bf16 [16384][32]    @ 16777216   ( 1 MiB)
//     Kb  bf16 [16384][32]    @ 17825792   ( 1 MiB)
//     Vf  bf16 frag-ordered   @ 18874368   ( 8 MiB)
//     Wf  bf16 frag-ordered   @ 27262976   ( 320 KiB)
// Vf: element (b,c,n) at b<<20 + (n>>5)*8192 + (c>>4)*512 + ((n>>3)&3)*128
//     + (c&15)*8 + (n&7)  -> MFMA B-frag = contiguous 1KB per wave.
// Wf: element (o,k) at (k>>5)*10240 + (o>>4)*512 + ((k>>3)&3)*128 + (o&15)*8
//     + (k&7)             -> same property.
// MFMA 16x16x32 bf16 layouts (m89/m120-verified):
//   A: lane holds A[m=lane&15][k=(lane>>4)*8+j]
//   B: lane holds B[k=(lane>>4)*8+j][n=lane&15]
//   C/D: lane holds D[row=(lane>>4)*4+r][col=lane&15]
// ---------------------------------------------------------------------------

// Kernel 1: 3x3 avg(/9, include-pad) + 3x3 max; blocks >=1024 do the W
// fp32->bf16 frag-order conversion (folded wcvt: one fewer dispatch).
__global__ __launch_bounds__(256) void pool_kernel(
    const float* __restrict__ x, ushort* __restrict__ cat,
    const float* __restrict__ wb, const float* __restrict__ wc,
    const float* __restrict__ wd, ushort* __restrict__ Wf) {
    int bid = blockIdx.x;
    int tid = threadIdx.x;
    if (bid >= 1024) {            // wcvt tail: 80 blocks x 4 frags
        int f = (bid - 1024) * 4 + (tid >> 6);   // 0..319
        int l = tid & 63;
        int ot = f % 20, kc = f / 20;
        int o = ot * 16 + (l & 15);
        int k0 = kc * 32 + (l >> 4) * 8;
        const float* wr = (o < 32) ? wb + (size_t)o * 512
                        : (o < 64) ? wc + (size_t)(o - 32) * 512
                                   : wd + (size_t)(o - 64) * 512;
        float4 f0 = *(const float4*)(wr + k0);
        float4 f1 = *(const float4*)(wr + k0 + 4);
        ushort tmp[8] = {f2u(f0.x), f2u(f0.y), f2u(f0.z), f2u(f0.w),
                         f2u(f1.x), f2u(f1.y), f2u(f1.z), f2u(f1.w)};
        *(uint4*)(Wf + kc * 10240 + ot * 512 + l * 8) = *(uint4*)tmp;
        return;
    }
    __shared__ float Xs[3][64][66];
    int b = bid >> 8, h = (bid >> 2) & 63, cg = bid & 3;
    bool hasU = (h > 0), hasD = (h < 63);
    #pragma unroll
    for (int pp = 0; pp < 12; ++pp) {
        int linear = pp * 256 + tid;
        int w4 = linear & 15;
        int cs = (linear >> 4) & 63;
        int dh = linear >> 10;
        int hh = h + dh - 1;
        float4 f = {0.f, 0.f, 0.f, 0.f};
        if ((unsigned)hh < 64u)
            f = *(const float4*)(x + ((size_t)(b * 256 + cg * 64 + cs)) * 4096
                                 + hh * 64 + w4 * 4);
        Xs[dh][w4 * 4 + 0][cs] = f.x;
        Xs[dh][w4 * 4 + 1][cs] = f.y;
        Xs[dh][w4 * 4 + 2][cs] = f.z;
        Xs[dh][w4 * 4 + 3][cs] = f.w;
    }
    __syncthreads();
    int cs = tid & 63, ws = tid >> 6;
    float vs[18], vm[18];
    #pragma unroll
    for (int j = 0; j < 18; ++j) {
        int w = ws * 16 - 1 + j;
        if ((unsigned)w < 64u) {
            float u = Xs[0][w][cs], m = Xs[1][w][cs], d = Xs[2][w][cs];
            vs[j] = u + m + d;
            float mx = m;
            if (hasU) mx = fmaxf(mx, u);
            if (hasD) mx = fmaxf(mx, d);
            vm[j] = mx;
        } else { vs[j] = 0.f; vm[j] = -3.4e38f; }
    }
    size_t nb = ((size_t)b * 4096 + h * 64 + ws * 16) * 512 + cg * 64 + cs;
    #pragma unroll
    for (int i = 0; i < 16; ++i) {
        float sum = vs[i] + vs[i + 1] + vs[i + 2];
        float mx  = fmaxf(fmaxf(vm[i], vm[i + 1]), vm[i + 2]);
        cat[nb + (size_t)i * 512]       = f2u(sum * (1.f / 9.f));
        cat[nb + (size_t)i * 512 + 256] = f2u(mx);
    }
}

// Kernel 2: single-pass projections (unchanged from r7).
__global__ __launch_bounds__(256, 2) void proj_kernel(
    const ushort* __restrict__ cat, const ushort* __restrict__ Wf,
    const float* __restrict__ bb, const float* __restrict__ bc,
    const float* __restrict__ bd,
    ushort* __restrict__ Qb, ushort* __restrict__ Kb, ushort* __restrict__ Vf) {
    __shared__ __align__(16) ushort As[32][72];
    __shared__ __align__(16) ushort Vls[256][40];
    int tid = threadIdx.x;
    int l = tid & 63, w = tid >> 6;
    int lm = l & 15, q = l >> 4;
    int n0 = blockIdx.x * 32;
    f4v acc[2][5];
    #pragma unroll
    for (int mt = 0; mt < 2; ++mt)
        #pragma unroll
        for (int ot = 0; ot < 5; ++ot)
            #pragma unroll
            for (int i = 0; i < 4; ++i) acc[mt][ot][i] = 0.f;

    const ushort* wfb = Wf + (w * 5) * 512 + l * 8;
    int sr = tid >> 3, sko = (tid & 7) * 8;
    const ushort* srow = cat + (size_t)(n0 + sr) * 512 + sko;

    for (int kc = 0; kc < 8; ++kc) {
        *(uint4*)&As[sr][sko] = *(const uint4*)(srow + kc * 64);
        __syncthreads();
        #pragma unroll
        for (int ks = 0; ks < 2; ++ks) {
            int kci = kc * 2 + ks;
            s8v bf[5];
            #pragma unroll
            for (int ot = 0; ot < 5; ++ot)
                bf[ot] = *(const s8v*)(wfb + kci * 10240 + ot * 512);
            s8v a0 = *(const s8v*)&As[lm][ks * 32 + q * 8];
            s8v a1 = *(const s8v*)&As[16 + lm][ks * 32 + q * 8];
            #pragma unroll
            for (int ot = 0; ot < 5; ++ot) {
                acc[0][ot] = __builtin_amdgcn_mfma_f32_16x16x32_bf16(a0, bf[ot], acc[0][ot], 0, 0, 0);
                acc[1][ot] = __builtin_amdgcn_mfma_f32_16x16x32_bf16(a1, bf[ot], acc[1][ot], 0, 0, 0);
            }
        }
        __syncthreads();
    }
    #pragma unroll
    for (int ot = 0; ot < 5; ++ot) {
        int o = w * 80 + ot * 16 + lm;
        if (o < 32) {
            float bias = bb[o];
            #pragma unroll
            for (int mt = 0; mt < 2; ++mt)
                #pragma unroll
                for (int r = 0; r < 4; ++r)
                    Qb[(size_t)(n0 + mt * 16 + q * 4 + r) * 32 + o]
                        = f2u(acc[mt][ot][r] + bias);
        } else if (o < 64) {
            float bias = bc[o - 32];
            #pragma unroll
            for (int mt = 0; mt < 2; ++mt)
                #pragma unroll
                for (int r = 0; r < 4; ++r)
                    Kb[(size_t)(n0 + mt * 16 + q * 4 + r) * 32 + (o - 32)]
                        = f2u(acc[mt][ot][r] + bias);
        } else {
            int c = o - 64;
            float bias = bd[c];
            #pragma unroll
            for (int mt = 0; mt < 2; ++mt) {
                ushort tmp[4];
                #pragma unroll
                for (int r = 0; r < 4; ++r) tmp[r] = f2u(acc[mt][ot][r] + bias);
                *(uint2*)&Vls[c][mt * 16 + q * 4] = *(uint2*)tmp;
            }
        }
    }
    __syncthreads();
    {
        int bidx = n0 >> 12;
        size_t fb = ((size_t)bidx << 20) + (size_t)((n0 & 4095) >> 5) * 8192 + l * 8;
        #pragma unroll
        for (int i = 0; i < 4; ++i) {
            int cb = w * 4 + i;
            *(uint4*)(Vf + fb + cb * 512) = *(const uint4*)&Vls[cb * 16 + lm][q * 8];
        }
    }
}

// Kernel 3: MFMA flash attention + residual. 256 blocks, 512 threads (8 waves,
// reverted from R1's 16-wave experiment: more TLP HURT -> bottleneck is the
// per-tile __syncthreads vmcnt(0) drain coupling all waves to the slowest L2
// return. Fix: raw `s_waitcnt lgkmcnt(0); s_barrier` (NO vmcnt drain) so the
// register V/K prefetches stay in flight across the barrier (T4: never drain
// vmcnt in the main loop). Compiler inserts counted vmcnt at first USE, one
// full tile after issue. LDS (Ps) ordering is fully covered by lgkmcnt(0).
// Body order: prefetch issue -> S MFMA -> Af ds_reads -> exp (covers ds_read
// latency) -> Ps write -> 16 PV MFMA -> lgkm-barrier.
__global__ __launch_bounds__(512, 2) void attn_kernel(
    const ushort* __restrict__ Qb, const ushort* __restrict__ Kb,
    const ushort* __restrict__ Vf, const float* __restrict__ x,
    const float* __restrict__ alphap, float* __restrict__ out) {
    __shared__ __align__(16) ushort Ps[2][64][72];
    __shared__ float Obuf[4][64][17];
    __shared__ float Lpart[4][64];
    __shared__ float Lrow[64];
    int tid = threadIdx.x;
    int l = tid & 63, w = tid >> 6;
    int lm = l & 15, q = l >> 4;
    int nsw = w & 3, kh = w >> 2;
    int bid = blockIdx.x;
    int xcd = bid & 7;
    int b = xcd & 3;
    int midx = (bid >> 3) + ((xcd >> 2) << 5);
    int m0 = midx << 6;
    size_t bN = (size_t)b << 12;

    s8v Qf[2];
    {
        const ushort* qb = Qb + (bN + m0 + kh * 32) * 32;
        Qf[0] = *(const s8v*)(qb + (size_t)(lm) * 32 + q * 8);
        Qf[1] = *(const s8v*)(qb + (size_t)(16 + lm) * 32 + q * 8);
    }
    const ushort* kbp = Kb + (bN + nsw * 16 + lm) * 32 + q * 8;
    const ushort* vfp = Vf + ((size_t)b << 20) + kh * 8192 + (nsw * 4) * 512 + l * 8;

    f4v acc[4][4];
    #pragma unroll
    for (int mt = 0; mt < 4; ++mt)
        #pragma unroll
        for (int ct = 0; ct < 4; ++ct)
            #pragma unroll
            for (int i = 0; i < 4; ++i) acc[mt][ct][i] = 0.f;
    float La0 = 0.f, La1 = 0.f;

    // prologue: kf0 = tile0, kf1 = tile1, vfA = tile0; compute P(0)
    s8v kf0 = *(const s8v*)kbp;
    s8v kf1 = *(const s8v*)(kbp + 2048);
    s8v vfA[4], vfB[4];
    #pragma unroll
    for (int ct = 0; ct < 4; ++ct) vfA[ct] = *(const s8v*)(vfp + ct * 512);
    {
        f4v S0 = {0.f, 0.f, 0.f, 0.f}, S1 = {0.f, 0.f, 0.f, 0.f};
        S0 = __builtin_amdgcn_mfma_f32_16x16x32_bf16(kf0, Qf[0], S0, 0, 0, 0);
        S1 = __builtin_amdgcn_mfma_f32_16x16x32_bf16(kf0, Qf[1], S1, 0, 0, 0);
        ushort e0[4], e1[4];
        #pragma unroll
        for (int r = 0; r < 4; ++r) {
            float f0 = __expf(fminf(S0[r], 60.f));
            float f1 = __expf(fminf(S1[r], 60.f));
            La0 += f0; La1 += f1;
            e0[r] = f2u(f0); e1[r] = f2u(f1);
        }
        *(uint2*)&Ps[0][kh * 32 + lm][nsw * 16 + q * 4]      = *(uint2*)e0;
        *(uint2*)&Ps[0][kh * 32 + 16 + lm][nsw * 16 + q * 4] = *(uint2*)e1;
    }
    __syncthreads();

// Phase(t): prefetch kf(t+2), vf(t+1) (registers, NOT drained at barrier);
// S(t+1) MFMA; Af<-Ps[p]; exp(t+1)+Ps[1-p] write (VALU covers ds_read
// latency); PV(t) x16; lgkm-only barrier.
#define TILE_BODY(TT, KFS, KFP, VCUR, VNXT)                                       \
    {                                                                             \
        int p = (TT) & 1;                                                         \
        if ((TT) < 62) KFP = *(const s8v*)(kbp + (size_t)((TT) + 2) * 2048);      \
        if ((TT) < 63) {                                                          \
            const ushort* vn = vfp + (size_t)((TT) + 1) * 16384;                  \
            _Pragma("unroll")                                                     \
            for (int ct = 0; ct < 4; ++ct)                                        \
                VNXT[ct] = *(const s8v*)(vn + ct * 512);                          \
        }                                                                         \
        f4v S0 = {0.f, 0.f, 0.f, 0.f}, S1 = {0.f, 0.f, 0.f, 0.f};                 \
        if ((TT) < 63) {                                                          \
            S0 = __builtin_amdgcn_mfma_f32_16x16x32_bf16(KFS, Qf[0], S0, 0, 0, 0);\
            S1 = __builtin_amdgcn_mfma_f32_16x16x32_bf16(KFS, Qf[1], S1, 0, 0, 0);\
        }                                                                         \
        s8v Af0 = *(const s8v*)&Ps[p][lm][kh * 32 + q * 8];                       \
        s8v Af1 = *(const s8v*)&Ps[p][16 + lm][kh * 32 + q * 8];                  \
        s8v Af2 = *(const s8v*)&Ps[p][32 + lm][kh * 32 + q * 8];                  \
        s8v Af3 = *(const s8v*)&Ps[p][48 + lm][kh * 32 + q * 8];                  \
        if ((TT) < 63) {                                                          \
            ushort e0[4], e1[4];                                                  \
            _Pragma("unroll")                                                     \
            for (int r = 0; r < 4; ++r) {                                         \
                float f0 = __expf(fminf(S0[r], 60.f));                            \
                float f1 = __expf(fminf(S1[r], 60.f));                            \
                La0 += f0; La1 += f1;                                             \
                e0[r] = f2u(f0); e1[r] = f2u(f1);                                 \
            }                                                                     \
            *(uint2*)&Ps[1 - p][kh * 32 + lm][nsw * 16 + q * 4]      = *(uint2*)e0;\
            *(uint2*)&Ps[1 - p][kh * 32 + 16 + lm][nsw * 16 + q * 4] = *(uint2*)e1;\
        }                                                                         \
        _Pragma("unroll")                                                         \
        for (int ct = 0; ct < 4; ++ct) {                                          \
            acc[0][ct] = __builtin_amdgcn_mfma_f32_16x16x32_bf16(Af0, VCUR[ct], acc[0][ct], 0, 0, 0); \
            acc[1][ct] = __builtin_amdgcn_mfma_f32_16x16x32_bf16(Af1, VCUR[ct], acc[1][ct], 0, 0, 0); \
            acc[2][ct] = __builtin_amdgcn_mfma_f32_16x16x32_bf16(Af2, VCUR[ct], acc[2][ct], 0, 0, 0); \
            acc[3][ct] = __builtin_amdgcn_mfma_f32_16x16x32_bf16(Af3, VCUR[ct], acc[3][ct], 0, 0, 0); \
        }                                                                         \
        asm volatile("s_waitcnt lgkmcnt(0)\n\ts_barrier" ::: "memory");           \
    }

    for (int t = 0; t < 64; t += 2) {
        TILE_BODY(t,     kf1, kf0, vfA, vfB);
        TILE_BODY(t + 1, kf0, kf1, vfB, vfA);
    }
#undef TILE_BODY

    // L: reduce over q groups (n-dir), then across nsw waves
    La0 += __shfl_xor(La0, 16, 64); La0 += __shfl_xor(La0, 32, 64);
    La1 += __shfl_xor(La1, 16, 64); La1 += __shfl_xor(La1, 32, 64);
    if (q == 0) {
        Lpart[nsw][kh * 32 + lm]      = La0;
        Lpart[nsw][kh * 32 + 16 + lm] = La1;
    }
    __syncthreads();
    if (tid < 64)
        Lrow[tid] = Lpart[0][tid] + Lpart[1][tid] + Lpart[2][tid] + Lpart[3][tid];
    __syncthreads();
    // combine k-halves through LDS
    #pragma unroll
    for (int ct = 0; ct < 4; ++ct) {
        if (kh == 1) {
            #pragma unroll
            for (int mt = 0; mt < 4; ++mt)
                #pragma unroll
                for (int r = 0; r < 4; ++r)
                    Obuf[nsw][mt * 16 + q * 4 + r][lm] = acc[mt][ct][r];
        }
        __syncthreads();
        if (kh == 0) {
            #pragma unroll
            for (int mt = 0; mt < 4; ++mt)
                #pragma unroll
                for (int r = 0; r < 4; ++r)
                    acc[mt][ct][r] += Obuf[nsw][mt * 16 + q * 4 + r][lm];
        }
        __syncthreads();
    }
    if (kh == 0) {
        float alpha = alphap[0];
        float ra = 1.f - alpha;
        #pragma unroll
        for (int mt = 0; mt < 4; ++mt) {
            float L0 = Lrow[mt * 16 + q * 4 + 0];
            float L1 = Lrow[mt * 16 + q * 4 + 1];
            float L2 = Lrow[mt * 16 + q * 4 + 2];
            float L3 = Lrow[mt * 16 + q * 4 + 3];
            #pragma unroll
            for (int ct = 0; ct < 4; ++ct) {
                int cc = nsw * 64 + ct * 16 + lm;
                size_t base = ((size_t)(b * 256 + cc)) * 4096 + m0 + mt * 16 + q * 4;
                float4 xv = *(const float4*)(x + base);
                float4 ov;
                ov.x = alpha * (acc[mt][ct][0] / L0) + ra * xv.x;
                ov.y = alpha * (acc[mt][ct][1] / L1) + ra * xv.y;
                ov.z = alpha * (acc[mt][ct][2] / L2) + ra * xv.z;
                ov.w = alpha * (acc[mt][ct][3] / L3) + ra * xv.w;
                *(float4*)(out + base) = ov;
            }
        }
    }
}

extern "C" void kernel_launch(void* const* d_in, const int* in_sizes, int n_in,
                              void* d_out, int out_size, void* d_ws, size_t ws_size,
                              hipStream_t stream) {
    const float* x  = (const float*)d_in[0];
    const float* wb = (const float*)d_in[1];
    const float* bb = (const float*)d_in[2];
    const float* wc = (const float*)d_in[3];
    const float* bc = (const float*)d_in[4];
    const float* wd = (const float*)d_in[5];
    const float* bd = (const float*)d_in[6];
    const float* al = (const float*)d_in[7];
    float* out = (float*)d_out;

    char* ws = (char*)d_ws;
    ushort* cat = (ushort*)ws;                    // 16 MiB
    ushort* Qb  = (ushort*)(ws + 16777216);       //  1 MiB
    ushort* Kb  = (ushort*)(ws + 17825792);       //  1 MiB
    ushort* Vf  = (ushort*)(ws + 18874368);       //  8 MiB (frag-ordered)
    ushort* Wf  = (ushort*)(ws + 27262976);       //  320 KiB (frag-ordered)

    pool_kernel<<<dim3(1104), dim3(256), 0, stream>>>(x, cat, wb, wc, wd, Wf);
    proj_kernel<<<dim3(512), dim3(256), 0, stream>>>(cat, Wf, bb, bc, bd,
                                                     Qb, Kb, Vf);
    attn_kernel<<<dim3(256), dim3(512), 0, stream>>>(Qb, Kb, Vf, x, al, out);
}

// Round 3
// 164.953 us; speedup vs baseline: 1.0509x; 1.0126x over previous
//
#include <hip/hip_runtime.h>
#include <hip/hip_bf16.h>

typedef __hip_bfloat16 bf16;
typedef __attribute__((ext_vector_type(8))) short s8v;   // 8 bf16 = 4 VGPR (MFMA A/B frag)
typedef __attribute__((ext_vector_type(4))) float f4v;   // MFMA C/D frag

__device__ __forceinline__ ushort f2u(float f) {
    bf16 h = __float2bfloat16(f);
    return *(ushort*)&h;
}

// ---------------------------------------------------------------------------
// B=4, C=256, H=W=64, N=4096. All inputs/outputs fp32; internal bf16.
// ws: cat bf16 [16384][512]   @ 0          (16 MiB)
//     Qb  bf16 [16384][32]    @ 16777216   ( 1 MiB)
//     Kb  bf16 [16384][32]    @ 17825792   ( 1 MiB)
//     Vf  bf16 frag-ordered   @ 18874368   ( 8 MiB)
//     Wf  bf16 frag-ordered   @ 27262976   ( 320 KiB)
// Vf: element (b,c,n) at b<<20 + (n>>5)*8192 + (c>>4)*512 + ((n>>3)&3)*128
//     + (c&15)*8 + (n&7)  -> MFMA B-frag = contiguous 1KB per wave.
// Wf: element (o,k) at (k>>5)*10240 + (o>>4)*512 + ((k>>3)&3)*128 + (o&15)*8
//     + (k&7)             -> same property.
// MFMA 16x16x32 bf16 layouts (m89/m120-verified):
//   A: lane holds A[m=lane&15][k=(lane>>4)*8+j]
//   B: lane holds B[k=(lane>>4)*8+j][n=lane&15]
//   C/D: lane holds D[row=(lane>>4)*4+r][col=lane&15]
// ---------------------------------------------------------------------------

// Kernel 1: 3x3 avg(/9, include-pad) + 3x3 max; blocks >=1024 do the W
// fp32->bf16 frag-order conversion (folded wcvt: one fewer dispatch).
__global__ __launch_bounds__(256) void pool_kernel(
    const float* __restrict__ x, ushort* __restrict__ cat,
    const float* __restrict__ wb, const float* __restrict__ wc,
    const float* __restrict__ wd, ushort* __restrict__ Wf) {
    int bid = blockIdx.x;
    int tid = threadIdx.x;
    if (bid >= 1024) {            // wcvt tail: 80 blocks x 4 frags
        int f = (bid - 1024) * 4 + (tid >> 6);   // 0..319
        int l = tid & 63;
        int ot = f % 20, kc = f / 20;
        int o = ot * 16 + (l & 15);
        int k0 = kc * 32 + (l >> 4) * 8;
        const float* wr = (o < 32) ? wb + (size_t)o * 512
                        : (o < 64) ? wc + (size_t)(o - 32) * 512
                                   : wd + (size_t)(o - 64) * 512;
        float4 f0 = *(const float4*)(wr + k0);
        float4 f1 = *(const float4*)(wr + k0 + 4);
        ushort tmp[8] = {f2u(f0.x), f2u(f0.y), f2u(f0.z), f2u(f0.w),
                         f2u(f1.x), f2u(f1.y), f2u(f1.z), f2u(f1.w)};
        *(uint4*)(Wf + kc * 10240 + ot * 512 + l * 8) = *(uint4*)tmp;
        return;
    }
    __shared__ float Xs[3][64][66];
    int b = bid >> 8, h = (bid >> 2) & 63, cg = bid & 3;
    bool hasU = (h > 0), hasD = (h < 63);
    #pragma unroll
    for (int pp = 0; pp < 12; ++pp) {
        int linear = pp * 256 + tid;
        int w4 = linear & 15;
        int cs = (linear >> 4) & 63;
        int dh = linear >> 10;
        int hh = h + dh - 1;
        float4 f = {0.f, 0.f, 0.f, 0.f};
        if ((unsigned)hh < 64u)
            f = *(const float4*)(x + ((size_t)(b * 256 + cg * 64 + cs)) * 4096
                                 + hh * 64 + w4 * 4);
        Xs[dh][w4 * 4 + 0][cs] = f.x;
        Xs[dh][w4 * 4 + 1][cs] = f.y;
        Xs[dh][w4 * 4 + 2][cs] = f.z;
        Xs[dh][w4 * 4 + 3][cs] = f.w;
    }
    __syncthreads();
    int cs = tid & 63, ws = tid >> 6;
    float vs[18], vm[18];
    #pragma unroll
    for (int j = 0; j < 18; ++j) {
        int w = ws * 16 - 1 + j;
        if ((unsigned)w < 64u) {
            float u = Xs[0][w][cs], m = Xs[1][w][cs], d = Xs[2][w][cs];
            vs[j] = u + m + d;
            float mx = m;
            if (hasU) mx = fmaxf(mx, u);
            if (hasD) mx = fmaxf(mx, d);
            vm[j] = mx;
        } else { vs[j] = 0.f; vm[j] = -3.4e38f; }
    }
    size_t nb = ((size_t)b * 4096 + h * 64 + ws * 16) * 512 + cg * 64 + cs;
    #pragma unroll
    for (int i = 0; i < 16; ++i) {
        float sum = vs[i] + vs[i + 1] + vs[i + 2];
        float mx  = fmaxf(fmaxf(vm[i], vm[i + 1]), vm[i + 2]);
        cat[nb + (size_t)i * 512]       = f2u(sum * (1.f / 9.f));
        cat[nb + (size_t)i * 512 + 256] = f2u(mx);
    }
}

// Kernel 2: single-pass projections (unchanged from r7).
__global__ __launch_bounds__(256, 2) void proj_kernel(
    const ushort* __restrict__ cat, const ushort* __restrict__ Wf,
    const float* __restrict__ bb, const float* __restrict__ bc,
    const float* __restrict__ bd,
    ushort* __restrict__ Qb, ushort* __restrict__ Kb, ushort* __restrict__ Vf) {
    __shared__ __align__(16) ushort As[32][72];
    __shared__ __align__(16) ushort Vls[256][40];
    int tid = threadIdx.x;
    int l = tid & 63, w = tid >> 6;
    int lm = l & 15, q = l >> 4;
    int n0 = blockIdx.x * 32;
    f4v acc[2][5];
    #pragma unroll
    for (int mt = 0; mt < 2; ++mt)
        #pragma unroll
        for (int ot = 0; ot < 5; ++ot)
            #pragma unroll
            for (int i = 0; i < 4; ++i) acc[mt][ot][i] = 0.f;

    const ushort* wfb = Wf + (w * 5) * 512 + l * 8;
    int sr = tid >> 3, sko = (tid & 7) * 8;
    const ushort* srow = cat + (size_t)(n0 + sr) * 512 + sko;

    for (int kc = 0; kc < 8; ++kc) {
        *(uint4*)&As[sr][sko] = *(const uint4*)(srow + kc * 64);
        __syncthreads();
        #pragma unroll
        for (int ks = 0; ks < 2; ++ks) {
            int kci = kc * 2 + ks;
            s8v bf[5];
            #pragma unroll
            for (int ot = 0; ot < 5; ++ot)
                bf[ot] = *(const s8v*)(wfb + kci * 10240 + ot * 512);
            s8v a0 = *(const s8v*)&As[lm][ks * 32 + q * 8];
            s8v a1 = *(const s8v*)&As[16 + lm][ks * 32 + q * 8];
            #pragma unroll
            for (int ot = 0; ot < 5; ++ot) {
                acc[0][ot] = __builtin_amdgcn_mfma_f32_16x16x32_bf16(a0, bf[ot], acc[0][ot], 0, 0, 0);
                acc[1][ot] = __builtin_amdgcn_mfma_f32_16x16x32_bf16(a1, bf[ot], acc[1][ot], 0, 0, 0);
            }
        }
        __syncthreads();
    }
    #pragma unroll
    for (int ot = 0; ot < 5; ++ot) {
        int o = w * 80 + ot * 16 + lm;
        if (o < 32) {
            float bias = bb[o];
            #pragma unroll
            for (int mt = 0; mt < 2; ++mt)
                #pragma unroll
                for (int r = 0; r < 4; ++r)
                    Qb[(size_t)(n0 + mt * 16 + q * 4 + r) * 32 + o]
                        = f2u(acc[mt][ot][r] + bias);
        } else if (o < 64) {
            float bias = bc[o - 32];
            #pragma unroll
            for (int mt = 0; mt < 2; ++mt)
                #pragma unroll
                for (int r = 0; r < 4; ++r)
                    Kb[(size_t)(n0 + mt * 16 + q * 4 + r) * 32 + (o - 32)]
                        = f2u(acc[mt][ot][r] + bias);
        } else {
            int c = o - 64;
            float bias = bd[c];
            #pragma unroll
            for (int mt = 0; mt < 2; ++mt) {
                ushort tmp[4];
                #pragma unroll
                for (int r = 0; r < 4; ++r) tmp[r] = f2u(acc[mt][ot][r] + bias);
                *(uint2*)&Vls[c][mt * 16 + q * 4] = *(uint2*)tmp;
            }
        }
    }
    __syncthreads();
    {
        int bidx = n0 >> 12;
        size_t fb = ((size_t)bidx << 20) + (size_t)((n0 & 4095) >> 5) * 8192 + l * 8;
        #pragma unroll
        for (int i = 0; i < 4; ++i) {
            int cb = w * 4 + i;
            *(uint4*)(Vf + fb + cb * 512) = *(const uint4*)&Vls[cb * 16 + lm][q * 8];
        }
    }
}

// Kernel 3: MFMA flash attention + residual. 256 blocks, 512 threads (8 waves).
// R3: wave-staggered phase bodies (T-D fix). SIMD s hosts waves s and s+4 ->
// kh differs -> one wave runs [Af,S,PV,exp,write] (MFMA-first) while its
// SIMD partner runs [S,exp,write,Af,PV] (VALU-first): MFMA and VALU pipes
// overlap across waves instead of aligning (m114: different-wave pipes are
// free). Scores computed at distance 2 (3 Ps buffers, pointer-rotated):
// phase t reads Ps(t) written two barriers ago, writes Ps(t+2) -> the
// exp->write->barrier->read serial tail no longer gates the next phase.
// K/V register prefetch distance 2. lgkm-only barrier (no vmcnt drain).
// setprio(1) around PV cluster (T5).
__global__ __launch_bounds__(512, 2) void attn_kernel(
    const ushort* __restrict__ Qb, const ushort* __restrict__ Kb,
    const ushort* __restrict__ Vf, const float* __restrict__ x,
    const float* __restrict__ alphap, float* __restrict__ out) {
    __shared__ __align__(16) ushort Ps[3][64][72];
    __shared__ float Obuf[4][64][17];
    __shared__ float Lpart[4][64];
    __shared__ float Lrow[64];
    int tid = threadIdx.x;
    int l = tid & 63, w = tid >> 6;
    int lm = l & 15, q = l >> 4;
    int nsw = w & 3, kh = w >> 2;
    int bid = blockIdx.x;
    int xcd = bid & 7;
    int b = xcd & 3;
    int midx = (bid >> 3) + ((xcd >> 2) << 5);
    int m0 = midx << 6;
    size_t bN = (size_t)b << 12;

    s8v Qf[2];
    {
        const ushort* qb = Qb + (bN + m0 + kh * 32) * 32;
        Qf[0] = *(const s8v*)(qb + (size_t)(lm) * 32 + q * 8);
        Qf[1] = *(const s8v*)(qb + (size_t)(16 + lm) * 32 + q * 8);
    }
    const ushort* kbp = Kb + (bN + nsw * 16 + lm) * 32 + q * 8;
    const ushort* vfp = Vf + ((size_t)b << 20) + kh * 8192 + (nsw * 4) * 512 + l * 8;

    f4v acc[4][4];
    #pragma unroll
    for (int mt = 0; mt < 4; ++mt)
        #pragma unroll
        for (int ct = 0; ct < 4; ++ct)
            #pragma unroll
            for (int i = 0; i < 4; ++i) acc[mt][ct][i] = 0.f;
    float La0 = 0.f, La1 = 0.f;

    ushort* pA = &Ps[0][0][0];   // holds tile t   (read this phase)
    ushort* pB = &Ps[1][0][0];   // holds tile t+1
    ushort* pC = &Ps[2][0][0];   // written with tile t+2 this phase

// exp+pack+store of one score tile into PDST
#define SCORE_TAIL(S0, S1, PDST)                                                  \
    {                                                                             \
        ushort e0[4], e1[4];                                                      \
        _Pragma("unroll")                                                         \
        for (int r = 0; r < 4; ++r) {                                             \
            float f0 = __expf(fminf(S0[r], 60.f));                                \
            float f1 = __expf(fminf(S1[r], 60.f));                                \
            La0 += f0; La1 += f1;                                                 \
            e0[r] = f2u(f0); e1[r] = f2u(f1);                                     \
        }                                                                         \
        *(uint2*)(PDST + (kh * 32 + lm) * 72 + nsw * 16 + q * 4)      = *(uint2*)e0; \
        *(uint2*)(PDST + (kh * 32 + 16 + lm) * 72 + nsw * 16 + q * 4) = *(uint2*)e1; \
    }

    // prologue: issue all loads first, then score tiles 0 and 1 into pA, pB.
    s8v k0 = *(const s8v*)kbp;
    s8v k1 = *(const s8v*)(kbp + 2048);
    s8v kfA = *(const s8v*)(kbp + 2 * 2048);   // kf(2)
    s8v kfB = *(const s8v*)(kbp + 3 * 2048);   // kf(3)
    s8v vfA[4], vfB[4];
    #pragma unroll
    for (int ct = 0; ct < 4; ++ct) vfA[ct] = *(const s8v*)(vfp + ct * 512);
    #pragma unroll
    for (int ct = 0; ct < 4; ++ct) vfB[ct] = *(const s8v*)(vfp + 16384 + ct * 512);
    {
        f4v S0 = {0.f, 0.f, 0.f, 0.f}, S1 = {0.f, 0.f, 0.f, 0.f};
        S0 = __builtin_amdgcn_mfma_f32_16x16x32_bf16(k0, Qf[0], S0, 0, 0, 0);
        S1 = __builtin_amdgcn_mfma_f32_16x16x32_bf16(k0, Qf[1], S1, 0, 0, 0);
        SCORE_TAIL(S0, S1, pA);
    }
    {
        f4v S0 = {0.f, 0.f, 0.f, 0.f}, S1 = {0.f, 0.f, 0.f, 0.f};
        S0 = __builtin_amdgcn_mfma_f32_16x16x32_bf16(k1, Qf[0], S0, 0, 0, 0);
        S1 = __builtin_amdgcn_mfma_f32_16x16x32_bf16(k1, Qf[1], S1, 0, 0, 0);
        SCORE_TAIL(S0, S1, pB);
    }
    __syncthreads();

    const ushort* kpa = kbp + 4 * 2048;      // refills for slot A: kf(4),kf(6),...
    const ushort* kpb = kbp + 5 * 2048;      // refills for slot B: kf(5),kf(7),...
    const ushort* vpa = vfp + 2 * 16384;     // refills for slot A: vf(2),vf(4),...
    const ushort* vpb = vfp + 3 * 16384;     // refills for slot B: vf(3),vf(5),...

// Phase(t): read Ps tile t from pA, write score tile t+2 to pC.
// kh=0 waves: MFMA-first order; kh=1 waves: VALU-first order.
#define PV_CLUSTER(VCUR)                                                          \
    __builtin_amdgcn_s_setprio(1);                                                \
    _Pragma("unroll")                                                             \
    for (int ct = 0; ct < 4; ++ct) {                                              \
        acc[0][ct] = __builtin_amdgcn_mfma_f32_16x16x32_bf16(Af0, VCUR[ct], acc[0][ct], 0, 0, 0); \
        acc[1][ct] = __builtin_amdgcn_mfma_f32_16x16x32_bf16(Af1, VCUR[ct], acc[1][ct], 0, 0, 0); \
        acc[2][ct] = __builtin_amdgcn_mfma_f32_16x16x32_bf16(Af2, VCUR[ct], acc[2][ct], 0, 0, 0); \
        acc[3][ct] = __builtin_amdgcn_mfma_f32_16x16x32_bf16(Af3, VCUR[ct], acc[3][ct], 0, 0, 0); \
    }                                                                             \
    __builtin_amdgcn_s_setprio(0);

#define TILE_BODY(TT, KFS, VCUR, KREF, VREF)                                      \
    {                                                                             \
        if (kh == 0) {                                                            \
            s8v Af0 = *(const s8v*)(pA + (lm) * 72 + q * 8);                      \
            s8v Af1 = *(const s8v*)(pA + (16 + lm) * 72 + q * 8);                 \
            s8v Af2 = *(const s8v*)(pA + (32 + lm) * 72 + q * 8);                 \
            s8v Af3 = *(const s8v*)(pA + (48 + lm) * 72 + q * 8);                 \
            f4v S0 = {0.f, 0.f, 0.f, 0.f}, S1 = {0.f, 0.f, 0.f, 0.f};             \
            if ((TT) < 62) {                                                      \
                S0 = __builtin_amdgcn_mfma_f32_16x16x32_bf16(KFS, Qf[0], S0, 0, 0, 0); \
                S1 = __builtin_amdgcn_mfma_f32_16x16x32_bf16(KFS, Qf[1], S1, 0, 0, 0); \
            }                                                                     \
            PV_CLUSTER(VCUR)                                                      \
            if ((TT) < 62) SCORE_TAIL(S0, S1, pC)                                 \
            if ((TT) < 60) { KFS = *(const s8v*)(KREF); KREF += 4096; }           \
            if ((TT) < 62) {                                                      \
                _Pragma("unroll")                                                 \
                for (int ct = 0; ct < 4; ++ct)                                    \
                    VCUR[ct] = *(const s8v*)(VREF + ct * 512);                    \
                VREF += 32768;                                                    \
            }                                                                     \
        } else {                                                                  \
            f4v S0 = {0.f, 0.f, 0.f, 0.f}, S1 = {0.f, 0.f, 0.f, 0.f};             \
            if ((TT) < 62) {                                                      \
                S0 = __builtin_amdgcn_mfma_f32_16x16x32_bf16(KFS, Qf[0], S0, 0, 0, 0); \
                S1 = __builtin_amdgcn_mfma_f32_16x16x32_bf16(KFS, Qf[1], S1, 0, 0, 0); \
                SCORE_TAIL(S0, S1, pC)                                            \
            }                                                                     \
            s8v Af0 = *(const s8v*)(pA + (lm) * 72 + 32 + q * 8);                 \
            s8v Af1 = *(const s8v*)(pA + (16 + lm) * 72 + 32 + q * 8);            \
            s8v Af2 = *(const s8v*)(pA + (32 + lm) * 72 + 32 + q * 8);            \
            s8v Af3 = *(const s8v*)(pA + (48 + lm) * 72 + 32 + q * 8);            \
            PV_CLUSTER(VCUR)                                                      \
            if ((TT) < 60) { KFS = *(const s8v*)(KREF); KREF += 4096; }           \
            if ((TT) < 62) {                                                      \
                _Pragma("unroll")                                                 \
                for (int ct = 0; ct < 4; ++ct)                                    \
                    VCUR[ct] = *(const s8v*)(VREF + ct * 512);                    \
                VREF += 32768;                                                    \
            }                                                                     \
        }                                                                         \
        asm volatile("s_waitcnt lgkmcnt(0)\n\ts_barrier" ::: "memory");           \
        { ushort* rot_ = pA; pA = pB; pB = pC; pC = rot_; }                       \
    }

    for (int t = 0; t < 64; t += 2) {
        TILE_BODY(t,     kfA, vfA, kpa, vpa);
        TILE_BODY(t + 1, kfB, vfB, kpb, vpb);
    }
#undef TILE_BODY
#undef PV_CLUSTER
#undef SCORE_TAIL

    // L: reduce over q groups (n-dir), then across nsw waves
    La0 += __shfl_xor(La0, 16, 64); La0 += __shfl_xor(La0, 32, 64);
    La1 += __shfl_xor(La1, 16, 64); La1 += __shfl_xor(La1, 32, 64);
    if (q == 0) {
        Lpart[nsw][kh * 32 + lm]      = La0;
        Lpart[nsw][kh * 32 + 16 + lm] = La1;
    }
    __syncthreads();
    if (tid < 64)
        Lrow[tid] = Lpart[0][tid] + Lpart[1][tid] + Lpart[2][tid] + Lpart[3][tid];
    __syncthreads();
    // combine k-halves through LDS
    #pragma unroll
    for (int ct = 0; ct < 4; ++ct) {
        if (kh == 1) {
            #pragma unroll
            for (int mt = 0; mt < 4; ++mt)
                #pragma unroll
                for (int r = 0; r < 4; ++r)
                    Obuf[nsw][mt * 16 + q * 4 + r][lm] = acc[mt][ct][r];
        }
        __syncthreads();
        if (kh == 0) {
            #pragma unroll
            for (int mt = 0; mt < 4; ++mt)
                #pragma unroll
                for (int r = 0; r < 4; ++r)
                    acc[mt][ct][r] += Obuf[nsw][mt * 16 + q * 4 + r][lm];
        }
        __syncthreads();
    }
    if (kh == 0) {
        float alpha = alphap[0];
        float ra = 1.f - alpha;
        #pragma unroll
        for (int mt = 0; mt < 4; ++mt) {
            float L0 = Lrow[mt * 16 + q * 4 + 0];
            float L1 = Lrow[mt * 16 + q * 4 + 1];
            float L2 = Lrow[mt * 16 + q * 4 + 2];
            float L3 = Lrow[mt * 16 + q * 4 + 3];
            #pragma unroll
            for (int ct = 0; ct < 4; ++ct) {
                int cc = nsw * 64 + ct * 16 + lm;
                size_t base = ((size_t)(b * 256 + cc)) * 4096 + m0 + mt * 16 + q * 4;
                float4 xv = *(const float4*)(x + base);
                float4 ov;
                ov.x = alpha * (acc[mt][ct][0] / L0) + ra * xv.x;
                ov.y = alpha * (acc[mt][ct][1] / L1) + ra * xv.y;
                ov.z = alpha * (acc[mt][ct][2] / L2) + ra * xv.z;
                ov.w = alpha * (acc[mt][ct][3] / L3) + ra * xv.w;
                *(float4*)(out + base) = ov;
            }
        }
    }
}

extern "C" void kernel_launch(void* const* d_in, const int* in_sizes, int n_in,
                              void* d_out, int out_size, void* d_ws, size_t ws_size,
                              hipStream_t stream) {
    const float* x  = (const float*)d_in[0];
    const float* wb = (const float*)d_in[1];
    const float* bb = (const float*)d_in[2];
    const float* wc = (const float*)d_in[3];
    const float* bc = (const float*)d_in[4];
    const float* wd = (const float*)d_in[5];
    const float* bd = (const float*)d_in[6];
    const float* al = (const float*)d_in[7];
    float* out = (float*)d_out;

    char* ws = (char*)d_ws;
    ushort* cat = (ushort*)ws;                    // 16 MiB
    ushort* Qb  = (ushort*)(ws + 16777216);       //  1 MiB
    ushort* Kb  = (ushort*)(ws + 17825792);       //  1 MiB
    ushort* Vf  = (ushort*)(ws + 18874368);       //  8 MiB (frag-ordered)
    ushort* Wf  = (ushort*)(ws + 27262976);       //  320 KiB (frag-ordered)

    pool_kernel<<<dim3(1104), dim3(256), 0, stream>>>(x, cat, wb, wc, wd, Wf);
    proj_kernel<<<dim3(512), dim3(256), 0, stream>>>(cat, Wf, bb, bc, bd,
                                                     Qb, Kb, Vf);
    attn_kernel<<<dim3(256), dim3(512), 0, stream>>>(Qb, Kb, Vf, x, al, out);
}

// Round 4
// 164.243 us; speedup vs baseline: 1.0555x; 1.0043x over previous
//
#include <hip/hip_runtime.h>
#include <hip/hip_bf16.h>

typedef __hip_bfloat16 bf16;
typedef __attribute__((ext_vector_type(8))) short s8v;   // 8 bf16 = 4 VGPR (MFMA A/B frag)
typedef __attribute__((ext_vector_type(4))) float f4v;   // MFMA C/D frag

__device__ __forceinline__ ushort f2u(float f) {
    bf16 h = __float2bfloat16(f);
    return *(ushort*)&h;
}

// ---------------------------------------------------------------------------
// B=4, C=256, H=W=64, N=4096. All inputs/outputs fp32; internal bf16.
// ws: Qb  bf16 [16384][32]    @ 0          ( 1 MiB)
//     Kb  bf16 [16384][32]    @ 1048576    ( 1 MiB)
//     Vf  bf16 frag-ordered   @ 2097152    ( 8 MiB)
//     Wf  bf16 frag-ordered   @ 10485760   ( 320 KiB)
// cat is GONE (R4): pool+proj fused; the 64x512 cat tile lives in LDS only.
// Vf: element (b,c,n) at b<<20 + (n>>5)*8192 + (c>>4)*512 + ((n>>3)&3)*128
//     + (c&15)*8 + (n&7)  -> MFMA B-frag = contiguous 1KB per wave.
// Wf: element (o,k) at (k>>5)*10240 + (o>>4)*512 + ((k>>3)&3)*128 + (o&15)*8
//     + (k&7)             -> same property.
// MFMA 16x16x32 bf16 layouts (m89/m120-verified):
//   A: lane holds A[m=lane&15][k=(lane>>4)*8+j]
//   B: lane holds B[k=(lane>>4)*8+j][n=lane&15]
//   C/D: lane holds D[row=(lane>>4)*4+r][col=lane&15]
// ---------------------------------------------------------------------------

// Kernel 1: W fp32 -> bf16 frag-order conversion. 80 blocks x 256 thr.
__global__ __launch_bounds__(256) void wcvt_kernel(
    const float* __restrict__ wb, const float* __restrict__ wc,
    const float* __restrict__ wd, ushort* __restrict__ Wf) {
    int f = blockIdx.x * 4 + (threadIdx.x >> 6);   // 0..319
    int l = threadIdx.x & 63;
    int ot = f % 20, kc = f / 20;
    int o = ot * 16 + (l & 15);
    int k0 = kc * 32 + (l >> 4) * 8;
    const float* wr = (o < 32) ? wb + (size_t)o * 512
                    : (o < 64) ? wc + (size_t)(o - 32) * 512
                               : wd + (size_t)(o - 64) * 512;
    float4 f0 = *(const float4*)(wr + k0);
    float4 f1 = *(const float4*)(wr + k0 + 4);
    ushort tmp[8] = {f2u(f0.x), f2u(f0.y), f2u(f0.z), f2u(f0.w),
                     f2u(f1.x), f2u(f1.y), f2u(f1.z), f2u(f1.w)};
    *(uint4*)(Wf + kc * 10240 + ot * 512 + l * 8) = *(uint4*)tmp;
}

// Kernel 2 (R4 fused): 3x3 avg(/9)+max pooling -> bf16 cat tile in LDS ->
// barrier-free projection K-loop -> Qb/Kb/Vf. 256 blocks (1/CU), 512 thr.
// Block = (b, h) = one full h-row of 64 output positions, all 512 cat-ch.
// Pooling: 4 cg iterations (64 ch each), x staged via Xs (fp32, 50.7KB),
// next-cg loads register-prefetched under current-cg compute.
// Proj: A-frags from catS (LDS, 520-pad -> uniform bank spread), B-frags
// from Wf (L2-resident, 320KB shared by all blocks), NO barriers in K-loop.
// XCD-chunked bid swizzle: adjacent h on same XCD -> halo rows L2-shared.
// LDS: Xs 50688 | catS 66560 = 117248 B -> 1 block/CU. Vls aliases Xs.
__global__ __launch_bounds__(512, 2) void fused_kernel(
    const float* __restrict__ x, const ushort* __restrict__ Wf,
    const float* __restrict__ bb, const float* __restrict__ bc,
    const float* __restrict__ bd,
    ushort* __restrict__ Qb, ushort* __restrict__ Kb, ushort* __restrict__ Vf) {
    __shared__ __align__(16) char smem[117248];
    float*  Xs   = (float*)smem;              // [3][64][66] fp32 (pool phase)
    ushort* Vls  = (ushort*)smem;             // [256][72]   (epilogue, aliases Xs)
    ushort* catS = (ushort*)(smem + 50688);   // [64][520]  bf16 cat tile

    int tid = threadIdx.x;
    int bid = blockIdx.x;
    int lb = (bid & 7) * 32 + (bid >> 3);     // XCD-chunk swizzle (8x32, bijective)
    int b = lb >> 6, h = lb & 63;
    bool hasU = (h > 0), hasD = (h < 63);

    // ---- pooling phase ----
    float4 xr[6];
#define LOADCG(CG)                                                              \
    {                                                                           \
        _Pragma("unroll")                                                       \
        for (int pp = 0; pp < 6; ++pp) {                                        \
            int linear = pp * 512 + tid;                                        \
            int w4 = linear & 15, cs_s = (linear >> 4) & 63, dh = linear >> 10; \
            int hh = h + dh - 1;                                                \
            float4 fv = {0.f, 0.f, 0.f, 0.f};                                   \
            if ((unsigned)hh < 64u)                                             \
                fv = *(const float4*)(x + ((size_t)(b * 256 + (CG) * 64 + cs_s)) * 4096 \
                                      + hh * 64 + w4 * 4);                      \
            xr[pp] = fv;                                                        \
        }                                                                       \
    }
    LOADCG(0)
    #pragma unroll
    for (int cg = 0; cg < 4; ++cg) {
        #pragma unroll
        for (int pp = 0; pp < 6; ++pp) {
            int linear = pp * 512 + tid;
            int w4 = linear & 15, cs_s = (linear >> 4) & 63, dh = linear >> 10;
            float* xp = Xs + (dh * 64 + w4 * 4) * 66 + cs_s;
            xp[0]   = xr[pp].x;
            xp[66]  = xr[pp].y;
            xp[132] = xr[pp].z;
            xp[198] = xr[pp].w;
        }
        __syncthreads();
        if (cg == 0) LOADCG(1)
        else if (cg == 1) LOADCG(2)
        else if (cg == 2) LOADCG(3)
        {
            int cs = tid & 63, wsw = tid >> 6;
            float vs[10], vm[10];
            #pragma unroll
            for (int j = 0; j < 10; ++j) {
                int w = wsw * 8 - 1 + j;
                if ((unsigned)w < 64u) {
                    float u = Xs[w * 66 + cs];
                    float m = Xs[(64 + w) * 66 + cs];
                    float d = Xs[(128 + w) * 66 + cs];
                    vs[j] = u + m + d;
                    float mx = m;
                    if (hasU) mx = fmaxf(mx, u);
                    if (hasD) mx = fmaxf(mx, d);
                    vm[j] = mx;
                } else { vs[j] = 0.f; vm[j] = -3.4e38f; }
            }
            int chb = cg * 64 + cs;
            #pragma unroll
            for (int i = 0; i < 8; ++i) {
                float sum = vs[i] + vs[i + 1] + vs[i + 2];
                float mx  = fmaxf(fmaxf(vm[i], vm[i + 1]), vm[i + 2]);
                catS[(wsw * 8 + i) * 520 + chb]       = f2u(sum * (1.f / 9.f));
                catS[(wsw * 8 + i) * 520 + 256 + chb] = f2u(mx);
            }
        }
        __syncthreads();
    }
#undef LOADCG

    // ---- projection phase (no barriers in K-loop) ----
    int l = tid & 63, w = tid >> 6;
    int lm = l & 15, q = l >> 4;
    int nc = w & 3, oh = w >> 2;        // wave = (n-chunk 16, o-half 160)
    f4v pacc[10];
    #pragma unroll
    for (int ot = 0; ot < 10; ++ot)
        #pragma unroll
        for (int i = 0; i < 4; ++i) pacc[ot][i] = 0.f;

    const ushort* wfp = Wf + (oh * 10) * 512 + l * 8;
    const ushort* ap  = catS + (nc * 16 + lm) * 520 + q * 8;
    #pragma unroll 2
    for (int kci = 0; kci < 16; ++kci) {
        s8v Af = *(const s8v*)(ap + kci * 32);
        s8v Bf[10];
        #pragma unroll
        for (int ot = 0; ot < 10; ++ot)
            Bf[ot] = *(const s8v*)(wfp + kci * 10240 + ot * 512);
        #pragma unroll
        for (int ot = 0; ot < 10; ++ot)
            pacc[ot] = __builtin_amdgcn_mfma_f32_16x16x32_bf16(Af, Bf[ot], pacc[ot], 0, 0, 0);
    }

    // ---- epilogue: Qb/Kb direct, V via Vls (frag re-order) ----
    size_t nrow = (size_t)((b << 12) + h * 64 + nc * 16 + q * 4);
    if (oh == 0) {
        #pragma unroll
        for (int ot = 0; ot < 2; ++ot) {
            int o = ot * 16 + lm;
            float bias = bb[o];
            #pragma unroll
            for (int r = 0; r < 4; ++r)
                Qb[(nrow + r) * 32 + o] = f2u(pacc[ot][r] + bias);
        }
        #pragma unroll
        for (int ot = 2; ot < 4; ++ot) {
            int o = ot * 16 + lm - 32;
            float bias = bc[o];
            #pragma unroll
            for (int r = 0; r < 4; ++r)
                Kb[(nrow + r) * 32 + o] = f2u(pacc[ot][r] + bias);
        }
        #pragma unroll
        for (int ot = 4; ot < 10; ++ot) {
            int c = ot * 16 + lm - 64;
            float bias = bd[c];
            ushort tmp[4];
            #pragma unroll
            for (int r = 0; r < 4; ++r) tmp[r] = f2u(pacc[ot][r] + bias);
            *(uint2*)&Vls[c * 72 + nc * 16 + q * 4] = *(uint2*)tmp;
        }
    } else {
        #pragma unroll
        for (int ot = 0; ot < 10; ++ot) {
            int c = 96 + ot * 16 + lm;
            float bias = bd[c];
            ushort tmp[4];
            #pragma unroll
            for (int r = 0; r < 4; ++r) tmp[r] = f2u(pacc[ot][r] + bias);
            *(uint2*)&Vls[c * 72 + nc * 16 + q * 4] = *(uint2*)tmp;
        }
    }
    __syncthreads();
    {
        size_t vb = ((size_t)b << 20) + (size_t)(h * 2) * 8192 + l * 8;
        #pragma unroll
        for (int i = 0; i < 2; ++i) {
            int cb = w * 2 + i;
            #pragma unroll
            for (int nh = 0; nh < 2; ++nh)
                *(uint4*)(Vf + vb + nh * 8192 + cb * 512)
                    = *(const uint4*)&Vls[(cb * 16 + lm) * 72 + nh * 32 + q * 8];
        }
    }
}

// Kernel 3: MFMA flash attention + residual. 256 blocks, 512 threads (8 waves).
// R2-best version (58.7 us): lgkm-only barrier (no vmcnt drain, T4), register
// K/V prefetch (K dist 2, V dist 1), 2-buffer Ps ping-pong, one barrier/tile.
__global__ __launch_bounds__(512, 2) void attn_kernel(
    const ushort* __restrict__ Qb, const ushort* __restrict__ Kb,
    const ushort* __restrict__ Vf, const float* __restrict__ x,
    const float* __restrict__ alphap, float* __restrict__ out) {
    __shared__ __align__(16) ushort Ps[2][64][72];
    __shared__ float Obuf[4][64][17];
    __shared__ float Lpart[4][64];
    __shared__ float Lrow[64];
    int tid = threadIdx.x;
    int l = tid & 63, w = tid >> 6;
    int lm = l & 15, q = l >> 4;
    int nsw = w & 3, kh = w >> 2;
    int bid = blockIdx.x;
    int xcd = bid & 7;
    int b = xcd & 3;
    int midx = (bid >> 3) + ((xcd >> 2) << 5);
    int m0 = midx << 6;
    size_t bN = (size_t)b << 12;

    s8v Qf[2];
    {
        const ushort* qb = Qb + (bN + m0 + kh * 32) * 32;
        Qf[0] = *(const s8v*)(qb + (size_t)(lm) * 32 + q * 8);
        Qf[1] = *(const s8v*)(qb + (size_t)(16 + lm) * 32 + q * 8);
    }
    const ushort* kbp = Kb + (bN + nsw * 16 + lm) * 32 + q * 8;
    const ushort* vfp = Vf + ((size_t)b << 20) + kh * 8192 + (nsw * 4) * 512 + l * 8;

    f4v acc[4][4];
    #pragma unroll
    for (int mt = 0; mt < 4; ++mt)
        #pragma unroll
        for (int ct = 0; ct < 4; ++ct)
            #pragma unroll
            for (int i = 0; i < 4; ++i) acc[mt][ct][i] = 0.f;
    float La0 = 0.f, La1 = 0.f;

    // prologue: kf0 = tile0, kf1 = tile1, vfA = tile0; compute P(0)
    s8v kf0 = *(const s8v*)kbp;
    s8v kf1 = *(const s8v*)(kbp + 2048);
    s8v vfA[4], vfB[4];
    #pragma unroll
    for (int ct = 0; ct < 4; ++ct) vfA[ct] = *(const s8v*)(vfp + ct * 512);
    {
        f4v S0 = {0.f, 0.f, 0.f, 0.f}, S1 = {0.f, 0.f, 0.f, 0.f};
        S0 = __builtin_amdgcn_mfma_f32_16x16x32_bf16(kf0, Qf[0], S0, 0, 0, 0);
        S1 = __builtin_amdgcn_mfma_f32_16x16x32_bf16(kf0, Qf[1], S1, 0, 0, 0);
        ushort e0[4], e1[4];
        #pragma unroll
        for (int r = 0; r < 4; ++r) {
            float f0 = __expf(fminf(S0[r], 60.f));
            float f1 = __expf(fminf(S1[r], 60.f));
            La0 += f0; La1 += f1;
            e0[r] = f2u(f0); e1[r] = f2u(f1);
        }
        *(uint2*)&Ps[0][kh * 32 + lm][nsw * 16 + q * 4]      = *(uint2*)e0;
        *(uint2*)&Ps[0][kh * 32 + 16 + lm][nsw * 16 + q * 4] = *(uint2*)e1;
    }
    __syncthreads();

// Phase(t): prefetch kf(t+2), vf(t+1) (registers, NOT drained at barrier);
// S(t+1) MFMA; Af<-Ps[p]; exp(t+1)+Ps[1-p] write (VALU covers ds_read
// latency); PV(t) x16; lgkm-only barrier.
#define TILE_BODY(TT, KFS, KFP, VCUR, VNXT)                                       \
    {                                                                             \
        int p = (TT) & 1;                                                         \
        if ((TT) < 62) KFP = *(const s8v*)(kbp + (size_t)((TT) + 2) * 2048);      \
        if ((TT) < 63) {                                                          \
            const ushort* vn = vfp + (size_t)((TT) + 1) * 16384;                  \
            _Pragma("unroll")                                                     \
            for (int ct = 0; ct < 4; ++ct)                                        \
                VNXT[ct] = *(const s8v*)(vn + ct * 512);                          \
        }                                                                         \
        f4v S0 = {0.f, 0.f, 0.f, 0.f}, S1 = {0.f, 0.f, 0.f, 0.f};                 \
        if ((TT) < 63) {                                                          \
            S0 = __builtin_amdgcn_mfma_f32_16x16x32_bf16(KFS, Qf[0], S0, 0, 0, 0);\
            S1 = __builtin_amdgcn_mfma_f32_16x16x32_bf16(KFS, Qf[1], S1, 0, 0, 0);\
        }                                                                         \
        s8v Af0 = *(const s8v*)&Ps[p][lm][kh * 32 + q * 8];                       \
        s8v Af1 = *(const s8v*)&Ps[p][16 + lm][kh * 32 + q * 8];                  \
        s8v Af2 = *(const s8v*)&Ps[p][32 + lm][kh * 32 + q * 8];                  \
        s8v Af3 = *(const s8v*)&Ps[p][48 + lm][kh * 32 + q * 8];                  \
        if ((TT) < 63) {                                                          \
            ushort e0[4], e1[4];                                                  \
            _Pragma("unroll")                                                     \
            for (int r = 0; r < 4; ++r) {                                         \
                float f0 = __expf(fminf(S0[r], 60.f));                            \
                float f1 = __expf(fminf(S1[r], 60.f));                            \
                La0 += f0; La1 += f1;                                             \
                e0[r] = f2u(f0); e1[r] = f2u(f1);                                 \
            }                                                                     \
            *(uint2*)&Ps[1 - p][kh * 32 + lm][nsw * 16 + q * 4]      = *(uint2*)e0;\
            *(uint2*)&Ps[1 - p][kh * 32 + 16 + lm][nsw * 16 + q * 4] = *(uint2*)e1;\
        }                                                                         \
        _Pragma("unroll")                                                         \
        for (int ct = 0; ct < 4; ++ct) {                                          \
            acc[0][ct] = __builtin_amdgcn_mfma_f32_16x16x32_bf16(Af0, VCUR[ct], acc[0][ct], 0, 0, 0); \
            acc[1][ct] = __builtin_amdgcn_mfma_f32_16x16x32_bf16(Af1, VCUR[ct], acc[1][ct], 0, 0, 0); \
            acc[2][ct] = __builtin_amdgcn_mfma_f32_16x16x32_bf16(Af2, VCUR[ct], acc[2][ct], 0, 0, 0); \
            acc[3][ct] = __builtin_amdgcn_mfma_f32_16x16x32_bf16(Af3, VCUR[ct], acc[3][ct], 0, 0, 0); \
        }                                                                         \
        asm volatile("s_waitcnt lgkmcnt(0)\n\ts_barrier" ::: "memory");           \
    }

    for (int t = 0; t < 64; t += 2) {
        TILE_BODY(t,     kf1, kf0, vfA, vfB);
        TILE_BODY(t + 1, kf0, kf1, vfB, vfA);
    }
#undef TILE_BODY

    // L: reduce over q groups (n-dir), then across nsw waves
    La0 += __shfl_xor(La0, 16, 64); La0 += __shfl_xor(La0, 32, 64);
    La1 += __shfl_xor(La1, 16, 64); La1 += __shfl_xor(La1, 32, 64);
    if (q == 0) {
        Lpart[nsw][kh * 32 + lm]      = La0;
        Lpart[nsw][kh * 32 + 16 + lm] = La1;
    }
    __syncthreads();
    if (tid < 64)
        Lrow[tid] = Lpart[0][tid] + Lpart[1][tid] + Lpart[2][tid] + Lpart[3][tid];
    __syncthreads();
    // combine k-halves through LDS
    #pragma unroll
    for (int ct = 0; ct < 4; ++ct) {
        if (kh == 1) {
            #pragma unroll
            for (int mt = 0; mt < 4; ++mt)
                #pragma unroll
                for (int r = 0; r < 4; ++r)
                    Obuf[nsw][mt * 16 + q * 4 + r][lm] = acc[mt][ct][r];
        }
        __syncthreads();
        if (kh == 0) {
            #pragma unroll
            for (int mt = 0; mt < 4; ++mt)
                #pragma unroll
                for (int r = 0; r < 4; ++r)
                    acc[mt][ct][r] += Obuf[nsw][mt * 16 + q * 4 + r][lm];
        }
        __syncthreads();
    }
    if (kh == 0) {
        float alpha = alphap[0];
        float ra = 1.f - alpha;
        #pragma unroll
        for (int mt = 0; mt < 4; ++mt) {
            float L0 = Lrow[mt * 16 + q * 4 + 0];
            float L1 = Lrow[mt * 16 + q * 4 + 1];
            float L2 = Lrow[mt * 16 + q * 4 + 2];
            float L3 = Lrow[mt * 16 + q * 4 + 3];
            #pragma unroll
            for (int ct = 0; ct < 4; ++ct) {
                int cc = nsw * 64 + ct * 16 + lm;
                size_t base = ((size_t)(b * 256 + cc)) * 4096 + m0 + mt * 16 + q * 4;
                float4 xv = *(const float4*)(x + base);
                float4 ov;
                ov.x = alpha * (acc[mt][ct][0] / L0) + ra * xv.x;
                ov.y = alpha * (acc[mt][ct][1] / L1) + ra * xv.y;
                ov.z = alpha * (acc[mt][ct][2] / L2) + ra * xv.z;
                ov.w = alpha * (acc[mt][ct][3] / L3) + ra * xv.w;
                *(float4*)(out + base) = ov;
            }
        }
    }
}

extern "C" void kernel_launch(void* const* d_in, const int* in_sizes, int n_in,
                              void* d_out, int out_size, void* d_ws, size_t ws_size,
                              hipStream_t stream) {
    const float* x  = (const float*)d_in[0];
    const float* wb = (const float*)d_in[1];
    const float* bb = (const float*)d_in[2];
    const float* wc = (const float*)d_in[3];
    const float* bc = (const float*)d_in[4];
    const float* wd = (const float*)d_in[5];
    const float* bd = (const float*)d_in[6];
    const float* al = (const float*)d_in[7];
    float* out = (float*)d_out;

    char* ws = (char*)d_ws;
    ushort* Qb = (ushort*)ws;                     // 1 MiB
    ushort* Kb = (ushort*)(ws + 1048576);         // 1 MiB
    ushort* Vf = (ushort*)(ws + 2097152);         // 8 MiB (frag-ordered)
    ushort* Wf = (ushort*)(ws + 10485760);        // 320 KiB (frag-ordered)

    wcvt_kernel<<<dim3(80), dim3(256), 0, stream>>>(wb, wc, wd, Wf);
    fused_kernel<<<dim3(256), dim3(512), 0, stream>>>(x, Wf, bb, bc, bd,
                                                      Qb, Kb, Vf);
    attn_kernel<<<dim3(256), dim3(512), 0, stream>>>(Qb, Kb, Vf, x, al, out);
}